// Round 4
// baseline (609.518 us; speedup 1.0000x reference)
//
#include <hip/hip_runtime.h>
#include <hip/hip_bf16.h>

typedef unsigned short u16;
typedef unsigned int u32;
typedef __bf16 bf16x8 __attribute__((ext_vector_type(8)));
typedef float f32x4 __attribute__((ext_vector_type(4)));

#define MFMA16(a, b, c) __builtin_amdgcn_mfma_f32_16x16x32_bf16((a), (b), (c), 0, 0, 0)

static __device__ __forceinline__ float bfbits2f(u32 b) {
    union { u32 u; float f; } c; c.u = b << 16; return c.f;
}
// round-to-nearest-even f32 -> bf16 bits
static __device__ __forceinline__ u32 f2bfbits(float f) {
    union { float f; u32 u; } c; c.f = f;
    return (c.u + 0x7FFFu + ((c.u >> 16) & 1u)) >> 16;
}
// exact for small integers (|v| <= 255): low 16 mantissa bits are zero
static __device__ __forceinline__ u32 f2bfbits_exact(float f) {
    union { float f; u32 u; } c; c.f = f;
    return c.u >> 16;
}

// ---------------- JAX threefry2x32, key = jax.random.key(42) -> (0, 42) -----
static __device__ __forceinline__ void threefry2x32(u32 c0, u32 c1, u32& o0, u32& o1) {
    const u32 k0 = 0u, k1 = 42u, k2 = 0u ^ 42u ^ 0x1BD11BDAu;
    u32 x0 = c0 + k0, x1 = c1 + k1;
#define TF_R4(ra, rb, rc, rd)                                   \
    x0 += x1; x1 = (x1 << ra) | (x1 >> (32 - ra)); x1 ^= x0;    \
    x0 += x1; x1 = (x1 << rb) | (x1 >> (32 - rb)); x1 ^= x0;    \
    x0 += x1; x1 = (x1 << rc) | (x1 >> (32 - rc)); x1 ^= x0;    \
    x0 += x1; x1 = (x1 << rd) | (x1 >> (32 - rd)); x1 ^= x0;
    TF_R4(13, 15, 26, 6)  x0 += k1; x1 += k2 + 1u;
    TF_R4(17, 29, 16, 24) x0 += k2; x1 += k0 + 2u;
    TF_R4(13, 15, 26, 6)  x0 += k0; x1 += k1 + 3u;
    TF_R4(17, 29, 16, 24) x0 += k1; x1 += k2 + 4u;
    TF_R4(13, 15, 26, 6)  x0 += k2; x1 += k0 + 5u;
#undef TF_R4
    o0 = x0; o1 = x1;
}

// XLA ErfInv (f32, Giles polynomial) — what jax lowers lax.erf_inv to
static __device__ __forceinline__ float xla_erfinv(float x) {
    float w = -log1pf(-x * x);
    float p;
    if (w < 5.0f) {
        w -= 2.5f;
        p = 2.81022636e-08f;
        p = fmaf(p, w, 3.43273939e-07f);
        p = fmaf(p, w, -3.5233877e-06f);
        p = fmaf(p, w, -4.39150654e-06f);
        p = fmaf(p, w, 0.00021858087f);
        p = fmaf(p, w, -0.00125372503f);
        p = fmaf(p, w, -0.00417768164f);
        p = fmaf(p, w, 0.246640727f);
        p = fmaf(p, w, 1.50140941f);
    } else {
        w = sqrtf(w) - 3.0f;
        p = -0.000200214257f;
        p = fmaf(p, w, 0.000100950558f);
        p = fmaf(p, w, 0.00134934322f);
        p = fmaf(p, w, -0.00367342844f);
        p = fmaf(p, w, 0.00573950773f);
        p = fmaf(p, w, -0.0076224613f);
        p = fmaf(p, w, 0.00943887047f);
        p = fmaf(p, w, 1.00167406f);
        p = fmaf(p, w, 2.83297682f);
    }
    return p * x;
}

// jax.random.normal(key(42), [4,16,1024,1024]) * 0.05 at flat index idx.
// Partitionable threefry (modern JAX default): counter = (hi=0, lo=idx),
// bits = x0 ^ x1; then uniform in [nextafter(-1,0), 1), sqrt(2)*erfinv.
static __device__ __forceinline__ float noise_at(u32 idx) {
    u32 x0, x1;
    threefry2x32(0u, idx, x0, x1);
    u32 bits = x0 ^ x1;
    float f = __uint_as_float((bits >> 9) | 0x3F800000u) - 1.0f;  // [0,1)
    float u = f * 2.0f - 0.99999994f;  // lo + f*(hi-lo); (hi-lo) rounds to 2.0f exactly
    u = fmaxf(-0.99999994f, u);
    return (sqrtf(2.0f) * xla_erfinv(u)) * 0.05f;
}

// ---------------- absmax over the 4 f32 tensors (u32 bit compare, sign stripped)
__global__ __launch_bounds__(256) void absmax_k(const float* __restrict__ h,
                                                const float* __restrict__ wq,
                                                const float* __restrict__ wk,
                                                const float* __restrict__ wv,
                                                u32* __restrict__ slots) {
    int t = blockIdx.y;
    const float* src = (t == 0) ? h : (t == 1) ? wq : (t == 2) ? wk : wv;
    int n4 = ((t == 0) ? 4096 * 1024 : 1024 * 1024) / 4;  // uint4 (4 floats) count
    u32 mx = 0;
    int tid = threadIdx.x;
    for (int i = blockIdx.x * blockDim.x + tid; i < n4; i += gridDim.x * blockDim.x) {
        uint4 v = ((const uint4*)src)[i];
        mx = max(mx, v.x & 0x7FFFFFFFu);
        mx = max(mx, v.y & 0x7FFFFFFFu);
        mx = max(mx, v.z & 0x7FFFFFFFu);
        mx = max(mx, v.w & 0x7FFFFFFFu);
    }
    __shared__ u32 red[256];
    red[tid] = mx;
    __syncthreads();
    for (int s = 128; s > 0; s >>= 1) {
        if (tid < s) red[tid] = max(red[tid], red[tid + s]);
        __syncthreads();
    }
    if (tid == 0) atomicMax(&slots[t], red[0]);
}

// ---------------- pre-quantize f32 -> exact-int bf16; optionally also raw bf16
__global__ __launch_bounds__(256) void prequant(const float* __restrict__ src,
                                                u16* __restrict__ dqi,
                                                u16* __restrict__ draw,
                                                const u32* __restrict__ slots,
                                                int slot, float qmax, int n8) {
    float amax = fmaxf(__uint_as_float(slots[slot]), 1e-8f);
    float scale = amax / qmax;  // IEEE f32, matches np
    for (int i = blockIdx.x * blockDim.x + threadIdx.x; i < n8; i += gridDim.x * blockDim.x) {
        float4 a = ((const float4*)src)[2 * i];
        float4 b = ((const float4*)src)[2 * i + 1];
        float x[8] = {a.x, a.y, a.z, a.w, b.x, b.y, b.z, b.w};
        u16 qi[8], rw[8];
#pragma unroll
        for (int j = 0; j < 8; j++) {
            float q = fminf(fmaxf(rintf(x[j] / scale), -qmax), qmax);  // IEEE div + half-even
            qi[j] = (u16)f2bfbits_exact(q);
            rw[j] = (u16)f2bfbits(x[j]);
        }
        *(uint4*)(dqi + 8 * (size_t)i) = *(const uint4*)qi;
        if (draw) *(uint4*)(draw + 8 * (size_t)i) = *(const uint4*)rw;
    }
}

// ---------------- projection GEMM: out[t,o] = oscale * sum_d A[t,d]*W[o,d]
// A: [4096][1024] bf16 (int values, or raw bf16 hidden), W: [1024][1024] bf16 int values
// transOut=0: out[((b*16+h)*1024+s)*64+dh]   (Q,K: [B,H,S,64])
// transOut=1: out[((b*16+h)*64+dh)*1024+s]   (V^T: [B,H,64,S])
__global__ __launch_bounds__(256) void qkv_gemm(const u16* __restrict__ A,
                                                const u16* __restrict__ Bw,
                                                const u32* __restrict__ slots,
                                                int wslot, int useAct, int transOut,
                                                u16* __restrict__ outp) {
    __shared__ __align__(16) u16 As[64 * 40];
    __shared__ __align__(16) u16 Bs[64 * 40];
    float s_a = fmaxf(__uint_as_float(slots[0]), 1e-8f) / 127.0f;
    float s_w = fmaxf(__uint_as_float(slots[wslot]), 1e-8f) / 7.0f;
    float oscale = useAct ? (s_a * s_w) : s_w;

    int tid = threadIdx.x;
    int srow = tid >> 2, scol = (tid & 3) * 8;
    int mbase = blockIdx.x * 64, nbase = blockIdx.y * 64;
    int lane = tid & 63, wv = tid >> 6;
    int quad = lane >> 4, l16 = lane & 15;

    f32x4 acc[4];
#pragma unroll
    for (int i = 0; i < 4; i++) acc[i] = (f32x4){0.f, 0.f, 0.f, 0.f};

    const u16* aptr = A + (size_t)(mbase + srow) * 1024 + scol;
    const u16* bptr = Bw + (size_t)(nbase + srow) * 1024 + scol;

    for (int k0 = 0; k0 < 1024; k0 += 32) {
        uint4 av = *(const uint4*)(aptr + k0);
        uint4 bv = *(const uint4*)(bptr + k0);
        __syncthreads();
        *(uint4*)(As + srow * 40 + scol) = av;
        *(uint4*)(Bs + srow * 40 + scol) = bv;
        __syncthreads();
        bf16x8 af = *(const bf16x8*)(As + (wv * 16 + l16) * 40 + quad * 8);
#pragma unroll
        for (int nt = 0; nt < 4; nt++) {
            bf16x8 bfr = *(const bf16x8*)(Bs + (nt * 16 + l16) * 40 + quad * 8);
            acc[nt] = MFMA16(af, bfr, acc[nt]);
        }
    }

#pragma unroll
    for (int nt = 0; nt < 4; nt++) {
#pragma unroll
        for (int r = 0; r < 4; r++) {
            float val = acc[nt][r] * oscale;
            int m = mbase + wv * 16 + quad * 4 + r;  // token
            int o = nbase + nt * 16 + l16;           // out-feature
            int b = m >> 10, s = m & 1023;
            int hh = o >> 6, dh = o & 63;
            size_t off = transOut ? (((size_t)(b * 16 + hh) * 64 + dh) * 1024 + s)
                                  : (((size_t)(b * 16 + hh) * 1024 + s) * 64 + dh);
            outp[off] = (u16)f2bfbits(val);
        }
    }
}

// ---------------- flash attention with inline threefry noise
// Q,K: [B,H,S,64] bf16; Vt: [B,H,64,S] bf16; mask: [B,1,1,S] f32 (zeros)
// Output: [B,S,H*64] FLOAT32 (the reference returns f32 -> d_out is float*)
__global__ __launch_bounds__(256) void attn_kernel(const u16* __restrict__ Q,
                                                   const u16* __restrict__ K,
                                                   const u16* __restrict__ Vt,
                                                   const float* __restrict__ mask,
                                                   float* __restrict__ outp) {
    __shared__ __align__(16) u16 Plds[4][16][40];  // per-wave P tile [q][k], +pad
    int qt = blockIdx.x, h = blockIdx.y, b = blockIdx.z;
    int bh = b * 16 + h;
    int tid = threadIdx.x, wv = tid >> 6, lane = tid & 63;
    int quad = lane >> 4, l16 = lane & 15;
    int q0 = qt * 64 + wv * 16;

    const u16* Qb = Q + (size_t)bh * 1024 * 64;
    const u16* Kb = K + (size_t)bh * 1024 * 64;
    const u16* Vb = Vt + (size_t)bh * 64 * 1024;

    bf16x8 aq0 = *(const bf16x8*)(Qb + (q0 + l16) * 64 + quad * 8);
    bf16x8 aq1 = *(const bf16x8*)(Qb + (q0 + l16) * 64 + 32 + quad * 8);

    f32x4 oacc[4];
#pragma unroll
    for (int i = 0; i < 4; i++) oacc[i] = (f32x4){0.f, 0.f, 0.f, 0.f};
    float mrun[4], lrun[4];
#pragma unroll
    for (int r = 0; r < 4; r++) { mrun[r] = -3.0e38f; lrun[r] = 0.f; }

    u16* myP = &Plds[wv][0][0];
    u32 idxbase = ((u32)bh * 1024u + (u32)(q0 + quad * 4)) * 1024u;

    for (int ks = 0; ks < 1024; ks += 32) {
        // ---- S = Q K^T for 16 q-rows x 32 k-cols
        f32x4 s0 = (f32x4){0.f, 0.f, 0.f, 0.f};
        f32x4 s1 = (f32x4){0.f, 0.f, 0.f, 0.f};
        const u16* Kt = Kb + (size_t)ks * 64;
        bf16x8 bk0 = *(const bf16x8*)(Kt + l16 * 64 + quad * 8);
        bf16x8 bk1 = *(const bf16x8*)(Kt + l16 * 64 + 32 + quad * 8);
        bf16x8 bk2 = *(const bf16x8*)(Kt + (16 + l16) * 64 + quad * 8);
        bf16x8 bk3 = *(const bf16x8*)(Kt + (16 + l16) * 64 + 32 + quad * 8);
        s0 = MFMA16(aq0, bk0, s0);
        s0 = MFMA16(aq1, bk1, s0);
        s1 = MFMA16(aq0, bk2, s1);
        s1 = MFMA16(aq1, bk3, s1);

        int kg0 = ks + l16;
        float mk0 = mask[b * 1024 + kg0];
        float mk1 = mask[b * 1024 + kg0 + 16];

        float sv0[4], sv1[4];
#pragma unroll
        for (int r = 0; r < 4; r++) {
            u32 idx = idxbase + (u32)r * 1024u + (u32)kg0;
            sv0[r] = s0[r] * 0.125f + noise_at(idx) + mk0;
            sv1[r] = s1[r] * 0.125f + noise_at(idx + 16u) + mk1;
        }

        // ---- online softmax (row stats across the 16 lanes of each quad)
#pragma unroll
        for (int r = 0; r < 4; r++) {
            float mx = fmaxf(sv0[r], sv1[r]);
            mx = fmaxf(mx, __shfl_xor(mx, 1));
            mx = fmaxf(mx, __shfl_xor(mx, 2));
            mx = fmaxf(mx, __shfl_xor(mx, 4));
            mx = fmaxf(mx, __shfl_xor(mx, 8));
            float mn = fmaxf(mrun[r], mx);
            float alpha = __expf(mrun[r] - mn);
            mrun[r] = mn;
            u32 p0b = f2bfbits(__expf(sv0[r] - mn));
            u32 p1b = f2bfbits(__expf(sv1[r] - mn));
            myP[(quad * 4 + r) * 40 + l16] = (u16)p0b;
            myP[(quad * 4 + r) * 40 + 16 + l16] = (u16)p1b;
            float ps = bfbits2f(p0b) + bfbits2f(p1b);  // consistent with MFMA'd P
            ps += __shfl_xor(ps, 1);
            ps += __shfl_xor(ps, 2);
            ps += __shfl_xor(ps, 4);
            ps += __shfl_xor(ps, 8);
            lrun[r] = lrun[r] * alpha + ps;
#pragma unroll
            for (int nt = 0; nt < 4; nt++) oacc[nt][r] *= alpha;
        }

        // ---- O += P V  (P read back from LDS in A-operand layout)
        __syncthreads();
        bf16x8 pf = *(const bf16x8*)(myP + l16 * 40 + quad * 8);
        __syncthreads();  // keep next iteration's P writes after this read
        const u16* Vk = Vb + ks;
#pragma unroll
        for (int nt = 0; nt < 4; nt++) {
            bf16x8 vf = *(const bf16x8*)(Vk + (nt * 16 + l16) * 1024 + quad * 8);
            oacc[nt] = MFMA16(pf, vf, oacc[nt]);
        }
    }

    // ---- epilogue: O / l, write [B,S,H*64] as FLOAT32
#pragma unroll
    for (int nt = 0; nt < 4; nt++) {
#pragma unroll
        for (int r = 0; r < 4; r++) {
            int q = q0 + quad * 4 + r;
            int dh = nt * 16 + l16;
            float val = oacc[nt][r] / lrun[r];
            outp[((size_t)(b * 1024 + q)) * 1024 + h * 64 + dh] = val;
        }
    }
}

extern "C" void kernel_launch(void* const* d_in, const int* in_sizes, int n_in,
                              void* d_out, int out_size, void* d_ws, size_t ws_size,
                              hipStream_t stream) {
    (void)in_sizes; (void)n_in; (void)out_size; (void)ws_size;
    const float* hidden = (const float*)d_in[0];
    const float* maskp  = (const float*)d_in[1];
    const float* Wq     = (const float*)d_in[2];
    const float* Wk     = (const float*)d_in[3];
    const float* Wv     = (const float*)d_in[4];
    float* outp = (float*)d_out;  // reference output dtype is float32

    char* ws = (char*)d_ws;
    u32* slots = (u32*)ws;                         // 4 x u32 (f32 bits of absmax)
    u16* hq  = (u16*)(ws + 256);                   // [4096][1024] int8 vals as bf16 (8 MB)
    u16* hbf = hq + 4096 * 1024;                   // [4096][1024] raw bf16 (8 MB)
    u16* wqi = hbf + 4096 * 1024;                  // [1024][1024] int4 vals as bf16 (2 MB)
    u16* wki = wqi + 1024 * 1024;
    u16* wvi = wki + 1024 * 1024;
    u16* Qb  = wvi + 1024 * 1024;                  // [B,H,S,64] (8 MB)
    u16* Kb  = Qb + 4096 * 1024;                   // [B,H,S,64] (8 MB)
    u16* Vtb = Kb + 4096 * 1024;                   // [B,H,64,S] (8 MB)

    hipMemsetAsync(slots, 0, 16, stream);
    absmax_k<<<dim3(128, 4), 256, 0, stream>>>(hidden, Wq, Wk, Wv, slots);
    prequant<<<dim3(256), 256, 0, stream>>>(hidden, hq, hbf, slots, 0, 127.0f, 4096 * 1024 / 8);
    prequant<<<dim3(64), 256, 0, stream>>>(Wq, wqi, nullptr, slots, 1, 7.0f, 1024 * 1024 / 8);
    prequant<<<dim3(64), 256, 0, stream>>>(Wk, wki, nullptr, slots, 2, 7.0f, 1024 * 1024 / 8);
    prequant<<<dim3(64), 256, 0, stream>>>(Wv, wvi, nullptr, slots, 3, 7.0f, 1024 * 1024 / 8);
    qkv_gemm<<<dim3(64, 16), 256, 0, stream>>>(hq, wqi, slots, 1, 1, 0, Qb);
    qkv_gemm<<<dim3(64, 16), 256, 0, stream>>>(hq, wki, slots, 2, 1, 0, Kb);
    qkv_gemm<<<dim3(64, 16), 256, 0, stream>>>(hbf, wvi, slots, 3, 0, 1, Vtb);
    attn_kernel<<<dim3(16, 16, 4), 256, 0, stream>>>(Qb, Kb, Vtb, maskp, outp);
}

// Round 5
// 411.155 us; speedup vs baseline: 1.4825x; 1.4825x over previous
//
#include <hip/hip_runtime.h>
#include <hip/hip_bf16.h>

typedef unsigned short u16;
typedef unsigned int u32;
typedef __bf16 bf16x8 __attribute__((ext_vector_type(8)));
typedef float f32x4 __attribute__((ext_vector_type(4)));

#define MFMA16(a, b, c) __builtin_amdgcn_mfma_f32_16x16x32_bf16((a), (b), (c), 0, 0, 0)

static __device__ __forceinline__ float bfbits2f(u32 b) {
    union { u32 u; float f; } c; c.u = b << 16; return c.f;
}
// round-to-nearest-even f32 -> bf16 bits
static __device__ __forceinline__ u32 f2bfbits(float f) {
    union { float f; u32 u; } c; c.f = f;
    return (c.u + 0x7FFFu + ((c.u >> 16) & 1u)) >> 16;
}
// exact for small integers (|v| <= 255): low 16 mantissa bits are zero
static __device__ __forceinline__ u32 f2bfbits_exact(float f) {
    union { float f; u32 u; } c; c.f = f;
    return c.u >> 16;
}

// ---------------- JAX threefry2x32, key = jax.random.key(42) -> (0, 42) -----
static __device__ __forceinline__ void threefry2x32(u32 c0, u32 c1, u32& o0, u32& o1) {
    const u32 k0 = 0u, k1 = 42u, k2 = 0u ^ 42u ^ 0x1BD11BDAu;
    u32 x0 = c0 + k0, x1 = c1 + k1;
#define TF_R4(ra, rb, rc, rd)                                   \
    x0 += x1; x1 = (x1 << ra) | (x1 >> (32 - ra)); x1 ^= x0;    \
    x0 += x1; x1 = (x1 << rb) | (x1 >> (32 - rb)); x1 ^= x0;    \
    x0 += x1; x1 = (x1 << rc) | (x1 >> (32 - rc)); x1 ^= x0;    \
    x0 += x1; x1 = (x1 << rd) | (x1 >> (32 - rd)); x1 ^= x0;
    TF_R4(13, 15, 26, 6)  x0 += k1; x1 += k2 + 1u;
    TF_R4(17, 29, 16, 24) x0 += k2; x1 += k0 + 2u;
    TF_R4(13, 15, 26, 6)  x0 += k0; x1 += k1 + 3u;
    TF_R4(17, 29, 16, 24) x0 += k1; x1 += k2 + 4u;
    TF_R4(13, 15, 26, 6)  x0 += k2; x1 += k0 + 5u;
#undef TF_R4
    o0 = x0; o1 = x1;
}

// jax.random.normal(key(42), [4,16,1024,1024]) * 0.05 at flat index idx.
// Partitionable threefry (HW-verified R4): counter = (0, idx), bits = x0^x1,
// uniform in [-0.99999994, 1), sqrt(2)*erfinv (XLA Giles poly).
// Fast-math path: fmaf(-u,u,1) is EXACT 1-u^2 (single rounding, no
// cancellation), __logf = v_log_f32 native (vs the fat log1pf libcall).
// Max deviation from XLA's log1p path ~1e-6 absolute — invisible at our
// 1.1e-2 tolerance (R4 margin: 4.9e-3 vs 11.2e-3).
static __device__ __forceinline__ float noise_at(u32 idx) {
    u32 x0, x1;
    threefry2x32(0u, idx, x0, x1);
    u32 bits = x0 ^ x1;
    float f = __uint_as_float((bits >> 9) | 0x3F800000u) - 1.0f;  // [0,1)
    float u = f * 2.0f - 0.99999994f;
    u = fmaxf(-0.99999994f, u);
    float t = fmaf(-u, u, 1.0f);       // exact 1-u^2
    float w = -__logf(t);              // native v_log_f32 * ln2
    float p;
    if (w < 5.0f) {
        float z = w - 2.5f;
        p = 2.81022636e-08f;
        p = fmaf(p, z, 3.43273939e-07f);
        p = fmaf(p, z, -3.5233877e-06f);
        p = fmaf(p, z, -4.39150654e-06f);
        p = fmaf(p, z, 0.00021858087f);
        p = fmaf(p, z, -0.00125372503f);
        p = fmaf(p, z, -0.00417768164f);
        p = fmaf(p, z, 0.246640727f);
        p = fmaf(p, z, 1.50140941f);
    } else {
        float z = sqrtf(w) - 3.0f;
        p = -0.000200214257f;
        p = fmaf(p, z, 0.000100950558f);
        p = fmaf(p, z, 0.00134934322f);
        p = fmaf(p, z, -0.00367342844f);
        p = fmaf(p, z, 0.00573950773f);
        p = fmaf(p, z, -0.0076224613f);
        p = fmaf(p, z, 0.00943887047f);
        p = fmaf(p, z, 1.00167406f);
        p = fmaf(p, z, 2.83297682f);
    }
    return (p * u) * 0.07071067811865475f;  // sqrt(2)*erfinv(u) * 0.05
}

// ---------------- absmax over the 4 f32 tensors (u32 bit compare, sign stripped)
__global__ __launch_bounds__(256) void absmax_k(const float* __restrict__ h,
                                                const float* __restrict__ wq,
                                                const float* __restrict__ wk,
                                                const float* __restrict__ wv,
                                                u32* __restrict__ slots) {
    int t = blockIdx.y;
    const float* src = (t == 0) ? h : (t == 1) ? wq : (t == 2) ? wk : wv;
    int n4 = ((t == 0) ? 4096 * 1024 : 1024 * 1024) / 4;  // uint4 (4 floats) count
    u32 mx = 0;
    int tid = threadIdx.x;
    for (int i = blockIdx.x * blockDim.x + tid; i < n4; i += gridDim.x * blockDim.x) {
        uint4 v = ((const uint4*)src)[i];
        mx = max(mx, v.x & 0x7FFFFFFFu);
        mx = max(mx, v.y & 0x7FFFFFFFu);
        mx = max(mx, v.z & 0x7FFFFFFFu);
        mx = max(mx, v.w & 0x7FFFFFFFu);
    }
    __shared__ u32 red[256];
    red[tid] = mx;
    __syncthreads();
    for (int s = 128; s > 0; s >>= 1) {
        if (tid < s) red[tid] = max(red[tid], red[tid + s]);
        __syncthreads();
    }
    if (tid == 0) atomicMax(&slots[t], red[0]);
}

// ---------------- pre-quantize f32 -> exact-int bf16; optionally also raw bf16
__global__ __launch_bounds__(256) void prequant(const float* __restrict__ src,
                                                u16* __restrict__ dqi,
                                                u16* __restrict__ draw,
                                                const u32* __restrict__ slots,
                                                int slot, float qmax, int n8) {
    float amax = fmaxf(__uint_as_float(slots[slot]), 1e-8f);
    float scale = amax / qmax;  // IEEE f32, matches np
    for (int i = blockIdx.x * blockDim.x + threadIdx.x; i < n8; i += gridDim.x * blockDim.x) {
        float4 a = ((const float4*)src)[2 * i];
        float4 b = ((const float4*)src)[2 * i + 1];
        float x[8] = {a.x, a.y, a.z, a.w, b.x, b.y, b.z, b.w};
        u16 qi[8], rw[8];
#pragma unroll
        for (int j = 0; j < 8; j++) {
            float q = fminf(fmaxf(rintf(x[j] / scale), -qmax), qmax);  // IEEE div + half-even
            qi[j] = (u16)f2bfbits_exact(q);
            rw[j] = (u16)f2bfbits(x[j]);
        }
        *(uint4*)(dqi + 8 * (size_t)i) = *(const uint4*)qi;
        if (draw) *(uint4*)(draw + 8 * (size_t)i) = *(const uint4*)rw;
    }
}

// ---------------- projection GEMM: out[t,o] = oscale * sum_d A[t,d]*W[o,d]
// A: [4096][1024] bf16 (int values, or raw bf16 hidden), W: [1024][1024] bf16 int values
// transOut=0: out[((b*16+h)*1024+s)*64+dh]   (Q,K: [B,H,S,64])
// transOut=1: out[((b*16+h)*64+dh)*1024+s]   (V^T: [B,H,64,S])
__global__ __launch_bounds__(256) void qkv_gemm(const u16* __restrict__ A,
                                                const u16* __restrict__ Bw,
                                                const u32* __restrict__ slots,
                                                int wslot, int useAct, int transOut,
                                                u16* __restrict__ outp) {
    __shared__ __align__(16) u16 As[64 * 40];
    __shared__ __align__(16) u16 Bs[64 * 40];
    float s_a = fmaxf(__uint_as_float(slots[0]), 1e-8f) / 127.0f;
    float s_w = fmaxf(__uint_as_float(slots[wslot]), 1e-8f) / 7.0f;
    float oscale = useAct ? (s_a * s_w) : s_w;

    int tid = threadIdx.x;
    int srow = tid >> 2, scol = (tid & 3) * 8;
    int mbase = blockIdx.x * 64, nbase = blockIdx.y * 64;
    int lane = tid & 63, wv = tid >> 6;
    int quad = lane >> 4, l16 = lane & 15;

    f32x4 acc[4];
#pragma unroll
    for (int i = 0; i < 4; i++) acc[i] = (f32x4){0.f, 0.f, 0.f, 0.f};

    const u16* aptr = A + (size_t)(mbase + srow) * 1024 + scol;
    const u16* bptr = Bw + (size_t)(nbase + srow) * 1024 + scol;

    for (int k0 = 0; k0 < 1024; k0 += 32) {
        uint4 av = *(const uint4*)(aptr + k0);
        uint4 bv = *(const uint4*)(bptr + k0);
        __syncthreads();
        *(uint4*)(As + srow * 40 + scol) = av;
        *(uint4*)(Bs + srow * 40 + scol) = bv;
        __syncthreads();
        bf16x8 af = *(const bf16x8*)(As + (wv * 16 + l16) * 40 + quad * 8);
#pragma unroll
        for (int nt = 0; nt < 4; nt++) {
            bf16x8 bfr = *(const bf16x8*)(Bs + (nt * 16 + l16) * 40 + quad * 8);
            acc[nt] = MFMA16(af, bfr, acc[nt]);
        }
    }

#pragma unroll
    for (int nt = 0; nt < 4; nt++) {
#pragma unroll
        for (int r = 0; r < 4; r++) {
            float val = acc[nt][r] * oscale;
            int m = mbase + wv * 16 + quad * 4 + r;  // token
            int o = nbase + nt * 16 + l16;           // out-feature
            int b = m >> 10, s = m & 1023;
            int hh = o >> 6, dh = o & 63;
            size_t off = transOut ? (((size_t)(b * 16 + hh) * 64 + dh) * 1024 + s)
                                  : (((size_t)(b * 16 + hh) * 1024 + s) * 64 + dh);
            outp[off] = (u16)f2bfbits(val);
        }
    }
}

// ---------------- flash attention with inline threefry noise
// Q,K: [B,H,S,64] bf16; Vt: [B,H,64,S] bf16; mask: [B,1,1,S] f32 (zeros)
// Output: [B,S,H*64] f32.
// Fixed-reference softmax (M=0): logits = qkt/8 + noise + mask are bounded
// (|s| ~< 10; exp overflow needs s>85), so p=exp(s), divide by Sigma p at the
// end — mathematically identical to max-subtracted softmax. Removes all
// online-max/alpha/shuffle machinery from the hot loop.
__global__ __launch_bounds__(256) void attn_kernel(const u16* __restrict__ Q,
                                                   const u16* __restrict__ K,
                                                   const u16* __restrict__ Vt,
                                                   const float* __restrict__ mask,
                                                   float* __restrict__ outp) {
    // double-buffered per-wave P tile: iter i writes/reads buf[i&1], so the
    // only hazard is same-iter RAW within one wave (HW DS pipe is in-order
    // per wave; asm memory clobbers pin compiler ordering).
    __shared__ __align__(16) u16 Plds[2][4][16][40];
    int qt = blockIdx.x, h = blockIdx.y, b = blockIdx.z;
    int bh = b * 16 + h;
    int tid = threadIdx.x, wv = tid >> 6, lane = tid & 63;
    int quad = lane >> 4, l16 = lane & 15;
    int q0 = qt * 64 + wv * 16;

    const u16* Qb = Q + (size_t)bh * 1024 * 64;
    const u16* Kb = K + (size_t)bh * 1024 * 64;
    const u16* Vb = Vt + (size_t)bh * 64 * 1024;

    bf16x8 aq0 = *(const bf16x8*)(Qb + (q0 + l16) * 64 + quad * 8);
    bf16x8 aq1 = *(const bf16x8*)(Qb + (q0 + l16) * 64 + 32 + quad * 8);

    f32x4 oacc[4];
#pragma unroll
    for (int i = 0; i < 4; i++) oacc[i] = (f32x4){0.f, 0.f, 0.f, 0.f};
    float lsum[4] = {0.f, 0.f, 0.f, 0.f};

    u16* Pw0 = &Plds[0][wv][0][0];
    u16* Pw1 = &Plds[1][wv][0][0];
    u32 idxbase = ((u32)bh * 1024u + (u32)(q0 + quad * 4)) * 1024u;

    for (int ks = 0; ks < 1024; ks += 32) {
        // ---- S = Q K^T for 16 q-rows x 32 k-cols
        f32x4 s0 = (f32x4){0.f, 0.f, 0.f, 0.f};
        f32x4 s1 = (f32x4){0.f, 0.f, 0.f, 0.f};
        const u16* Kt = Kb + (size_t)ks * 64;
        bf16x8 bk0 = *(const bf16x8*)(Kt + l16 * 64 + quad * 8);
        bf16x8 bk1 = *(const bf16x8*)(Kt + l16 * 64 + 32 + quad * 8);
        bf16x8 bk2 = *(const bf16x8*)(Kt + (16 + l16) * 64 + quad * 8);
        bf16x8 bk3 = *(const bf16x8*)(Kt + (16 + l16) * 64 + 32 + quad * 8);
        s0 = MFMA16(aq0, bk0, s0);
        s0 = MFMA16(aq1, bk1, s0);
        s1 = MFMA16(aq0, bk2, s1);
        s1 = MFMA16(aq1, bk3, s1);

        int kg0 = ks + l16;
        float mk0 = mask[b * 1024 + kg0];
        float mk1 = mask[b * 1024 + kg0 + 16];

        u16* myP = ((ks >> 5) & 1) ? Pw1 : Pw0;
#pragma unroll
        for (int r = 0; r < 4; r++) {
            u32 idx = idxbase + (u32)r * 1024u + (u32)kg0;
            float sv0 = s0[r] * 0.125f + noise_at(idx) + mk0;
            float sv1 = s1[r] * 0.125f + noise_at(idx + 16u) + mk1;
            u32 p0b = f2bfbits(__expf(sv0));
            u32 p1b = f2bfbits(__expf(sv1));
            myP[(quad * 4 + r) * 40 + l16] = (u16)p0b;
            myP[(quad * 4 + r) * 40 + 16 + l16] = (u16)p1b;
            lsum[r] += bfbits2f(p0b) + bfbits2f(p1b);  // consistent with MFMA'd P
        }

        // ---- O += P V  (P read back from LDS in A-operand layout)
        asm volatile("" ::: "memory");  // writes above stay above the read
        bf16x8 pf = *(const bf16x8*)(myP + l16 * 40 + quad * 8);
        asm volatile("" ::: "memory");  // later writes stay below the read
        const u16* Vk = Vb + ks;
#pragma unroll
        for (int nt = 0; nt < 4; nt++) {
            bf16x8 vf = *(const bf16x8*)(Vk + (nt * 16 + l16) * 1024 + quad * 8);
            oacc[nt] = MFMA16(pf, vf, oacc[nt]);
        }
    }

    // ---- epilogue: reduce l over the 16 lanes of each quad, O/l, write f32
    float linv[4];
#pragma unroll
    for (int r = 0; r < 4; r++) {
        float l = lsum[r];
        l += __shfl_xor(l, 1);
        l += __shfl_xor(l, 2);
        l += __shfl_xor(l, 4);
        l += __shfl_xor(l, 8);
        linv[r] = 1.0f / l;  // IEEE divide, once per row
    }
#pragma unroll
    for (int nt = 0; nt < 4; nt++) {
#pragma unroll
        for (int r = 0; r < 4; r++) {
            int q = q0 + quad * 4 + r;
            int dh = nt * 16 + l16;
            outp[((size_t)(b * 1024 + q)) * 1024 + h * 64 + dh] = oacc[nt][r] * linv[r];
        }
    }
}

extern "C" void kernel_launch(void* const* d_in, const int* in_sizes, int n_in,
                              void* d_out, int out_size, void* d_ws, size_t ws_size,
                              hipStream_t stream) {
    (void)in_sizes; (void)n_in; (void)out_size; (void)ws_size;
    const float* hidden = (const float*)d_in[0];
    const float* maskp  = (const float*)d_in[1];
    const float* Wq     = (const float*)d_in[2];
    const float* Wk     = (const float*)d_in[3];
    const float* Wv     = (const float*)d_in[4];
    float* outp = (float*)d_out;  // reference output dtype is float32

    char* ws = (char*)d_ws;
    u32* slots = (u32*)ws;                         // 4 x u32 (f32 bits of absmax)
    u16* hq  = (u16*)(ws + 256);                   // [4096][1024] int8 vals as bf16 (8 MB)
    u16* hbf = hq + 4096 * 1024;                   // [4096][1024] raw bf16 (8 MB)
    u16* wqi = hbf + 4096 * 1024;                  // [1024][1024] int4 vals as bf16 (2 MB)
    u16* wki = wqi + 1024 * 1024;
    u16* wvi = wki + 1024 * 1024;
    u16* Qb  = wvi + 1024 * 1024;                  // [B,H,S,64] (8 MB)
    u16* Kb  = Qb + 4096 * 1024;                   // [B,H,S,64] (8 MB)
    u16* Vtb = Kb + 4096 * 1024;                   // [B,H,64,S] (8 MB)

    hipMemsetAsync(slots, 0, 16, stream);
    absmax_k<<<dim3(128, 4), 256, 0, stream>>>(hidden, Wq, Wk, Wv, slots);
    prequant<<<dim3(256), 256, 0, stream>>>(hidden, hq, hbf, slots, 0, 127.0f, 4096 * 1024 / 8);
    prequant<<<dim3(64), 256, 0, stream>>>(Wq, wqi, nullptr, slots, 1, 7.0f, 1024 * 1024 / 8);
    prequant<<<dim3(64), 256, 0, stream>>>(Wk, wki, nullptr, slots, 2, 7.0f, 1024 * 1024 / 8);
    prequant<<<dim3(64), 256, 0, stream>>>(Wv, wvi, nullptr, slots, 3, 7.0f, 1024 * 1024 / 8);
    qkv_gemm<<<dim3(64, 16), 256, 0, stream>>>(hq, wqi, slots, 1, 1, 0, Qb);
    qkv_gemm<<<dim3(64, 16), 256, 0, stream>>>(hq, wki, slots, 2, 1, 0, Kb);
    qkv_gemm<<<dim3(64, 16), 256, 0, stream>>>(hbf, wvi, slots, 3, 0, 1, Vtb);
    attn_kernel<<<dim3(16, 16, 4), 256, 0, stream>>>(Qb, Kb, Vtb, maskp, outp);
}

// Round 6
// 392.198 us; speedup vs baseline: 1.5541x; 1.0483x over previous
//
#include <hip/hip_runtime.h>
#include <hip/hip_bf16.h>

typedef unsigned short u16;
typedef unsigned int u32;
typedef __bf16 bf16x8 __attribute__((ext_vector_type(8)));
typedef float f32x4 __attribute__((ext_vector_type(4)));

#define MFMA16(a, b, c) __builtin_amdgcn_mfma_f32_16x16x32_bf16((a), (b), (c), 0, 0, 0)

static __device__ __forceinline__ float bfbits2f(u32 b) {
    union { u32 u; float f; } c; c.u = b << 16; return c.f;
}
// round-to-nearest-even f32 -> bf16 bits
static __device__ __forceinline__ u32 f2bfbits(float f) {
    union { float f; u32 u; } c; c.f = f;
    return (c.u + 0x7FFFu + ((c.u >> 16) & 1u)) >> 16;
}
// exact for small integers (|v| <= 255): low 16 mantissa bits are zero
static __device__ __forceinline__ u32 f2bfbits_exact(float f) {
    union { float f; u32 u; } c; c.f = f;
    return c.u >> 16;
}
// packed RNE f32x2 -> bf16x2 (v_cvt_pk_bf16_f32 on gfx950)
static __device__ __forceinline__ u32 pack_bf16x2(float lo, float hi) {
    float2 v; v.x = lo; v.y = hi;
    union { __hip_bfloat162 h; u32 u; } c;
    c.h = __float22bfloat162_rn(v);
    return c.u;  // low 16 = lo, high 16 = hi
}

// ---------------- JAX threefry2x32, key = jax.random.key(42) -> (0, 42) -----
// __builtin_rotateleft32 guarantees v_alignbit_b32 (1 instr/rotate); the
// (x<<r)|(x>>(32-r)) idiom risks a 3-instr expansion -> +40 instr/draw.
static __device__ __forceinline__ void threefry2x32(u32 c0, u32 c1, u32& o0, u32& o1) {
    const u32 k0 = 0u, k1 = 42u, k2 = 0u ^ 42u ^ 0x1BD11BDAu;
    u32 x0 = c0 + k0, x1 = c1 + k1;
#define TF_R(r) x0 += x1; x1 = __builtin_rotateleft32(x1, r); x1 ^= x0;
    TF_R(13) TF_R(15) TF_R(26) TF_R(6)   x0 += k1; x1 += k2 + 1u;
    TF_R(17) TF_R(29) TF_R(16) TF_R(24)  x0 += k2; x1 += k0 + 2u;
    TF_R(13) TF_R(15) TF_R(26) TF_R(6)   x0 += k0; x1 += k1 + 3u;
    TF_R(17) TF_R(29) TF_R(16) TF_R(24)  x0 += k1; x1 += k2 + 4u;
    TF_R(13) TF_R(15) TF_R(26) TF_R(6)   x0 += k2; x1 += k0 + 5u;
#undef TF_R
    o0 = x0; o1 = x1;
}

// jax.random.normal(key(42), ...) at flat index idx, WITHOUT the final *0.05:
// returns p*u where sqrt(2)*erfinv(u) = p*u*sqrt(2)... (caller applies
// 0.05*sqrt(2) scale inside an fma). Partitionable threefry (HW-verified):
// counter = (0, idx), bits = x0^x1, uniform in [-0.99999994, 1).
static __device__ __forceinline__ float noise_pu(u32 idx) {
    u32 x0, x1;
    threefry2x32(0u, idx, x0, x1);
    u32 bits = x0 ^ x1;
    float f = __uint_as_float((bits >> 9) | 0x3F800000u) - 1.0f;  // [0,1)
    float u = f * 2.0f - 0.99999994f;
    u = fmaxf(-0.99999994f, u);
    float t = fmaf(-u, u, 1.0f);        // exact 1-u^2 (single rounding)
    float lg = __logf(t);               // native v_log_f32 path
    float p;
    if (lg > -5.0f) {                   // w = -lg < 5
        float z = fmaf(lg, -1.0f, -2.5f);  // w - 2.5, one fma
        p = 2.81022636e-08f;
        p = fmaf(p, z, 3.43273939e-07f);
        p = fmaf(p, z, -3.5233877e-06f);
        p = fmaf(p, z, -4.39150654e-06f);
        p = fmaf(p, z, 0.00021858087f);
        p = fmaf(p, z, -0.00125372503f);
        p = fmaf(p, z, -0.00417768164f);
        p = fmaf(p, z, 0.246640727f);
        p = fmaf(p, z, 1.50140941f);
    } else {
        float z = sqrtf(-lg) - 3.0f;
        p = -0.000200214257f;
        p = fmaf(p, z, 0.000100950558f);
        p = fmaf(p, z, 0.00134934322f);
        p = fmaf(p, z, -0.00367342844f);
        p = fmaf(p, z, 0.00573950773f);
        p = fmaf(p, z, -0.0076224613f);
        p = fmaf(p, z, 0.00943887047f);
        p = fmaf(p, z, 1.00167406f);
        p = fmaf(p, z, 2.83297682f);
    }
    return p * u;  // erfinv(u); caller: fma(pu, 0.07071068, base)
}

// ---------------- absmax over the 4 f32 tensors (u32 bit compare, sign stripped)
__global__ __launch_bounds__(256) void absmax_k(const float* __restrict__ h,
                                                const float* __restrict__ wq,
                                                const float* __restrict__ wk,
                                                const float* __restrict__ wv,
                                                u32* __restrict__ slots) {
    int t = blockIdx.y;
    const float* src = (t == 0) ? h : (t == 1) ? wq : (t == 2) ? wk : wv;
    int n4 = ((t == 0) ? 4096 * 1024 : 1024 * 1024) / 4;
    u32 mx = 0;
    int tid = threadIdx.x;
    for (int i = blockIdx.x * blockDim.x + tid; i < n4; i += gridDim.x * blockDim.x) {
        uint4 v = ((const uint4*)src)[i];
        mx = max(mx, v.x & 0x7FFFFFFFu);
        mx = max(mx, v.y & 0x7FFFFFFFu);
        mx = max(mx, v.z & 0x7FFFFFFFu);
        mx = max(mx, v.w & 0x7FFFFFFFu);
    }
    __shared__ u32 red[256];
    red[tid] = mx;
    __syncthreads();
    for (int s = 128; s > 0; s >>= 1) {
        if (tid < s) red[tid] = max(red[tid], red[tid + s]);
        __syncthreads();
    }
    if (tid == 0) atomicMax(&slots[t], red[0]);
}

// ---------------- merged pre-quantize: y=0 hidden (8-bit, + raw bf16 copy),
// y=1..3 weights (4-bit)
__global__ __launch_bounds__(256) void prequant_all(const float* __restrict__ hidden,
                                                    const float* __restrict__ wq,
                                                    const float* __restrict__ wk,
                                                    const float* __restrict__ wv,
                                                    u16* __restrict__ hq,
                                                    u16* __restrict__ hbf,
                                                    u16* __restrict__ wqi,
                                                    u16* __restrict__ wki,
                                                    u16* __restrict__ wvi,
                                                    const u32* __restrict__ slots) {
    int y = blockIdx.y;
    const float* src = (y == 0) ? hidden : (y == 1) ? wq : (y == 2) ? wk : wv;
    u16* dqi = (y == 0) ? hq : (y == 1) ? wqi : (y == 2) ? wki : wvi;
    u16* draw = (y == 0) ? hbf : nullptr;
    float qmax = (y == 0) ? 127.0f : 7.0f;
    int n8 = ((y == 0) ? 4096 * 1024 : 1024 * 1024) / 8;

    float amax = fmaxf(__uint_as_float(slots[y]), 1e-8f);
    float scale = amax / qmax;  // IEEE f32, matches np
    for (int i = blockIdx.x * blockDim.x + threadIdx.x; i < n8; i += gridDim.x * blockDim.x) {
        float4 a = ((const float4*)src)[2 * i];
        float4 b = ((const float4*)src)[2 * i + 1];
        float x[8] = {a.x, a.y, a.z, a.w, b.x, b.y, b.z, b.w};
        u16 qi[8], rw[8];
#pragma unroll
        for (int j = 0; j < 8; j++) {
            float q = fminf(fmaxf(rintf(x[j] / scale), -qmax), qmax);  // IEEE div + half-even
            qi[j] = (u16)f2bfbits_exact(q);
            rw[j] = (u16)f2bfbits(x[j]);
        }
        *(uint4*)(dqi + 8 * (size_t)i) = *(const uint4*)qi;
        if (draw) *(uint4*)(draw + 8 * (size_t)i) = *(const uint4*)rw;
    }
}

// ---------------- merged projection GEMMs: z=0 Q, z=1 K, z=2 V^T
// out[t,o] = oscale * sum_d A[t,d]*W[o,d]
__global__ __launch_bounds__(256) void qkv_gemm_all(const u16* __restrict__ hq,
                                                    const u16* __restrict__ hbf,
                                                    const u16* __restrict__ wqi,
                                                    const u16* __restrict__ wki,
                                                    const u16* __restrict__ wvi,
                                                    const u32* __restrict__ slots,
                                                    u16* __restrict__ Qb,
                                                    u16* __restrict__ Kb,
                                                    u16* __restrict__ Vtb) {
    __shared__ __align__(16) u16 As[64 * 40];
    __shared__ __align__(16) u16 Bs[64 * 40];
    int z = blockIdx.z;
    const u16* A  = (z < 2) ? hq : hbf;
    const u16* Bw = (z == 0) ? wqi : (z == 1) ? wki : wvi;
    u16* outp     = (z == 0) ? Qb : (z == 1) ? Kb : Vtb;
    int transOut = (z == 2);
    float s_a = fmaxf(__uint_as_float(slots[0]), 1e-8f) / 127.0f;
    float s_w = fmaxf(__uint_as_float(slots[z + 1]), 1e-8f) / 7.0f;
    float oscale = (z < 2) ? (s_a * s_w) : s_w;

    int tid = threadIdx.x;
    int srow = tid >> 2, scol = (tid & 3) * 8;
    int mbase = blockIdx.x * 64, nbase = blockIdx.y * 64;
    int lane = tid & 63, wv = tid >> 6;
    int quad = lane >> 4, l16 = lane & 15;

    f32x4 acc[4];
#pragma unroll
    for (int i = 0; i < 4; i++) acc[i] = (f32x4){0.f, 0.f, 0.f, 0.f};

    const u16* aptr = A + (size_t)(mbase + srow) * 1024 + scol;
    const u16* bptr = Bw + (size_t)(nbase + srow) * 1024 + scol;

    for (int k0 = 0; k0 < 1024; k0 += 32) {
        uint4 av = *(const uint4*)(aptr + k0);
        uint4 bv = *(const uint4*)(bptr + k0);
        __syncthreads();
        *(uint4*)(As + srow * 40 + scol) = av;
        *(uint4*)(Bs + srow * 40 + scol) = bv;
        __syncthreads();
        bf16x8 af = *(const bf16x8*)(As + (wv * 16 + l16) * 40 + quad * 8);
#pragma unroll
        for (int nt = 0; nt < 4; nt++) {
            bf16x8 bfr = *(const bf16x8*)(Bs + (nt * 16 + l16) * 40 + quad * 8);
            acc[nt] = MFMA16(af, bfr, acc[nt]);
        }
    }

#pragma unroll
    for (int nt = 0; nt < 4; nt++) {
#pragma unroll
        for (int r = 0; r < 4; r++) {
            float val = acc[nt][r] * oscale;
            int m = mbase + wv * 16 + quad * 4 + r;  // token
            int o = nbase + nt * 16 + l16;           // out-feature
            int b = m >> 10, s = m & 1023;
            int hh = o >> 6, dh = o & 63;
            size_t off = transOut ? (((size_t)(b * 16 + hh) * 64 + dh) * 1024 + s)
                                  : (((size_t)(b * 16 + hh) * 1024 + s) * 64 + dh);
            outp[off] = (u16)f2bfbits(val);
        }
    }
}

// ---------------- flash attention with inline threefry noise
// Q,K: [B,H,S,64] bf16; Vt: [B,H,64,S] bf16; mask: [B,1,1,S] f32; out f32.
// Fixed-reference softmax (M=0): logits bounded, exp cannot overflow.
__global__ __launch_bounds__(256) void attn_kernel(const u16* __restrict__ Q,
                                                   const u16* __restrict__ K,
                                                   const u16* __restrict__ Vt,
                                                   const float* __restrict__ mask,
                                                   float* __restrict__ outp) {
    // double-buffered per-wave P tile (R5-verified: asm fences + parity)
    __shared__ __align__(16) u16 Plds[2][4][16][40];
    int qt = blockIdx.x, h = blockIdx.y, b = blockIdx.z;
    int bh = b * 16 + h;
    int tid = threadIdx.x, wv = tid >> 6, lane = tid & 63;
    int quad = lane >> 4, l16 = lane & 15;
    int q0 = qt * 64 + wv * 16;

    const u16* Qb = Q + (size_t)bh * 1024 * 64;
    const u16* Kb = K + (size_t)bh * 1024 * 64;
    const u16* Vb = Vt + (size_t)bh * 64 * 1024;

    bf16x8 aq0 = *(const bf16x8*)(Qb + (q0 + l16) * 64 + quad * 8);
    bf16x8 aq1 = *(const bf16x8*)(Qb + (q0 + l16) * 64 + 32 + quad * 8);

    f32x4 oacc[4];
#pragma unroll
    for (int i = 0; i < 4; i++) oacc[i] = (f32x4){0.f, 0.f, 0.f, 0.f};
    float lsum[4] = {0.f, 0.f, 0.f, 0.f};

    u16* Pw0 = &Plds[0][wv][0][0];
    u16* Pw1 = &Plds[1][wv][0][0];
    u32 idxbase = ((u32)bh * 1024u + (u32)(q0 + quad * 4)) * 1024u;

    for (int ks = 0; ks < 1024; ks += 32) {
        // ---- S = Q K^T for 16 q-rows x 32 k-cols
        f32x4 s0 = (f32x4){0.f, 0.f, 0.f, 0.f};
        f32x4 s1 = (f32x4){0.f, 0.f, 0.f, 0.f};
        const u16* Kt = Kb + (size_t)ks * 64;
        bf16x8 bk0 = *(const bf16x8*)(Kt + l16 * 64 + quad * 8);
        bf16x8 bk1 = *(const bf16x8*)(Kt + l16 * 64 + 32 + quad * 8);
        bf16x8 bk2 = *(const bf16x8*)(Kt + (16 + l16) * 64 + quad * 8);
        bf16x8 bk3 = *(const bf16x8*)(Kt + (16 + l16) * 64 + 32 + quad * 8);
        s0 = MFMA16(aq0, bk0, s0);
        s0 = MFMA16(aq1, bk1, s0);
        s1 = MFMA16(aq0, bk2, s1);
        s1 = MFMA16(aq1, bk3, s1);

        int kg0 = ks + l16;
        float mk0 = mask[b * 1024 + kg0];
        float mk1 = mask[b * 1024 + kg0 + 16];

        u16* myP = ((ks >> 5) & 1) ? Pw1 : Pw0;
#pragma unroll
        for (int r = 0; r < 4; r++) {
            u32 idx = idxbase + (u32)r * 1024u + (u32)kg0;
            float pu0 = noise_pu(idx);
            float pu1 = noise_pu(idx + 16u);
            // 0.07071068 = 0.05*sqrt(2); logit = qkt/8 + noise + mask
            float sv0 = fmaf(pu0, 0.07071067811865475f, fmaf(s0[r], 0.125f, mk0));
            float sv1 = fmaf(pu1, 0.07071067811865475f, fmaf(s1[r], 0.125f, mk1));
            u32 pk = pack_bf16x2(__expf(sv0), __expf(sv1));  // v_cvt_pk_bf16_f32
            myP[(quad * 4 + r) * 40 + l16] = (u16)pk;
            myP[(quad * 4 + r) * 40 + 16 + l16] = (u16)(pk >> 16);
            lsum[r] += bfbits2f(pk & 0xFFFFu) + bfbits2f(pk >> 16);
        }

        // ---- O += P V  (P read back from LDS in A-operand layout)
        asm volatile("" ::: "memory");  // writes above stay above the read
        bf16x8 pf = *(const bf16x8*)(myP + l16 * 40 + quad * 8);
        asm volatile("" ::: "memory");  // later writes stay below the read
        const u16* Vk = Vb + ks;
#pragma unroll
        for (int nt = 0; nt < 4; nt++) {
            bf16x8 vf = *(const bf16x8*)(Vk + (nt * 16 + l16) * 1024 + quad * 8);
            oacc[nt] = MFMA16(pf, vf, oacc[nt]);
        }
    }

    // ---- epilogue: reduce l over the 16 lanes of each quad, O/l, write f32
    float linv[4];
#pragma unroll
    for (int r = 0; r < 4; r++) {
        float l = lsum[r];
        l += __shfl_xor(l, 1);
        l += __shfl_xor(l, 2);
        l += __shfl_xor(l, 4);
        l += __shfl_xor(l, 8);
        linv[r] = 1.0f / l;
    }
#pragma unroll
    for (int nt = 0; nt < 4; nt++) {
#pragma unroll
        for (int r = 0; r < 4; r++) {
            int q = q0 + quad * 4 + r;
            int dh = nt * 16 + l16;
            outp[((size_t)(b * 1024 + q)) * 1024 + h * 64 + dh] = oacc[nt][r] * linv[r];
        }
    }
}

extern "C" void kernel_launch(void* const* d_in, const int* in_sizes, int n_in,
                              void* d_out, int out_size, void* d_ws, size_t ws_size,
                              hipStream_t stream) {
    (void)in_sizes; (void)n_in; (void)out_size; (void)ws_size;
    const float* hidden = (const float*)d_in[0];
    const float* maskp  = (const float*)d_in[1];
    const float* Wq     = (const float*)d_in[2];
    const float* Wk     = (const float*)d_in[3];
    const float* Wv     = (const float*)d_in[4];
    float* outp = (float*)d_out;  // reference output dtype is float32

    char* ws = (char*)d_ws;
    u32* slots = (u32*)ws;                         // 4 x u32 (f32 bits of absmax)
    u16* hq  = (u16*)(ws + 256);                   // [4096][1024] int8 vals as bf16 (8 MB)
    u16* hbf = hq + 4096 * 1024;                   // [4096][1024] raw bf16 (8 MB)
    u16* wqi = hbf + 4096 * 1024;                  // [1024][1024] int4 vals as bf16 (2 MB)
    u16* wki = wqi + 1024 * 1024;
    u16* wvi = wki + 1024 * 1024;
    u16* Qb  = wvi + 1024 * 1024;                  // [B,H,S,64] (8 MB)
    u16* Kb  = Qb + 4096 * 1024;                   // [B,H,S,64] (8 MB)
    u16* Vtb = Kb + 4096 * 1024;                   // [B,H,64,S] (8 MB)

    hipMemsetAsync(slots, 0, 16, stream);
    absmax_k<<<dim3(128, 4), 256, 0, stream>>>(hidden, Wq, Wk, Wv, slots);
    prequant_all<<<dim3(64, 4), 256, 0, stream>>>(hidden, Wq, Wk, Wv,
                                                  hq, hbf, wqi, wki, wvi, slots);
    qkv_gemm_all<<<dim3(64, 16, 3), 256, 0, stream>>>(hq, hbf, wqi, wki, wvi, slots,
                                                      Qb, Kb, Vtb);
    attn_kernel<<<dim3(16, 16, 4), 256, 0, stream>>>(Qb, Kb, Vtb, maskp, outp);
}